// Round 12
// baseline (77.349 us; speedup 1.0000x reference)
//
#include <hip/hip_runtime.h>
#include <math.h>

// SWALP global block-quantize, sampled-bound speculate+fix (R12):
//   k0: strided sample (every 64th float4, spans whole array) -> per-block
//       max -> ws2[256]. Lower bound Ms <= Mg, same pow2 bucket as Mg w.h.p.
//   k1: each block loads its 7168-elem slice into registers (7 v4f/thread),
//       block max merged with Ms -> partial[b] = max(mb, Ms); quantize with
//       e_used = exp_floor(partial[b]) (== e_g for every block when Ms lands
//       in Mg's pow2 bucket), nt-store. Single x read, no spill (28 VGPRs).
//   k2: reduce partial -> e_g; blocks with exp_floor(partial[b]) == e_g exit
//       (expected: ALL); stragglers requantize from x with e_g -> bit-exact.
// Deterministic: no atomics; fix set is a pure function of the input.
// Traffic: ~13 (sample) + 205.5R + 205.5W + ~0 fix = ~424 MB (R11: ~476).

#define NB0 256                 // sample kernel blocks
#define NT 256
#define SAMPLE_N 200704         // n4 / 64
#define NB 7168                 // spec blocks; NB*NT*CH*4 == n exactly
#define CH 7                    // float4 per thread; slice = NT*CH = 1792 float4
#define GRID1 2048              // fallback grid

typedef float v4f __attribute__((ext_vector_type(4)));

__device__ inline int exp_floor(float m) {          // floor(log2|m|), floored at -120
    int eb = (int)((__float_as_uint(m) >> 23) & 0xff);
    int e = (eb == 0) ? -120 : eb - 127;
    return max(-120, min(127, e));
}
__device__ inline float exp2i(int k) {              // 2^k, k in [-126,127]
    return __uint_as_float((unsigned)(k + 127) << 23);
}
__device__ inline float absmax4(v4f v) {
    return fmaxf(fmaxf(fabsf(v.x), fabsf(v.y)), fmaxf(fabsf(v.z), fabsf(v.w)));
}
__device__ inline v4f quant4(v4f v, float s, float inv) {
    float a = fminf(fmaxf(rintf(v.x * s), -128.0f), 127.0f);
    float b = fminf(fmaxf(rintf(v.y * s), -128.0f), 127.0f);
    float c = fminf(fmaxf(rintf(v.z * s), -128.0f), 127.0f);
    float d = fminf(fmaxf(rintf(v.w * s), -128.0f), 127.0f);
    v4f r;
    r.x = a * inv; r.y = b * inv; r.z = c * inv; r.w = d * inv;
    return r;
}
__device__ inline float block_max_reduce(float m, int t) {
    #pragma unroll
    for (int off = 32; off > 0; off >>= 1)
        m = fmaxf(m, __shfl_xor(m, off, 64));
    __shared__ float sm[4];
    if ((t & 63) == 0) sm[t >> 6] = m;
    __syncthreads();
    return fmaxf(fmaxf(sm[0], sm[1]), fmaxf(sm[2], sm[3]));
}

__global__ __launch_bounds__(NT) void bq_sample(const float* __restrict__ x,
                                                float* __restrict__ ws2) {
    const v4f* __restrict__ x4 = (const v4f*)x;
    const int gtid = blockIdx.x * NT + threadIdx.x;
    float m = 0.0f;
    for (int i = gtid; i < SAMPLE_N; i += NB0 * NT)
        m = fmaxf(m, absmax4(x4[(size_t)i << 6]));
    const float mb = block_max_reduce(m, threadIdx.x);
    if (threadIdx.x == 0) ws2[blockIdx.x] = mb;
}

__global__ __launch_bounds__(NT) void bq_spec(const float* __restrict__ x,
                                              float* __restrict__ out,
                                              float* __restrict__ partial,
                                              const float* __restrict__ ws2) {
    const v4f* __restrict__ x4 = (const v4f*)x + (size_t)blockIdx.x * (NT * CH);
    v4f* __restrict__ o4 = (v4f*)out + (size_t)blockIdx.x * (NT * CH);
    const int t = threadIdx.x;

    v4f v[CH];
    #pragma unroll
    for (int k = 0; k < CH; ++k)
        v[k] = x4[k * NT + t];

    float m = ws2[t];                 // NT == NB0: merge sampled bound Ms
    #pragma unroll
    for (int k = 0; k < CH; ++k)
        m = fmaxf(m, absmax4(v[k]));
    const float mb = block_max_reduce(m, t);   // = max(block max, Ms)
    if (t == 0) partial[blockIdx.x] = mb;

    const int e = exp_floor(mb);
    const float s = exp2i(6 - e), inv = exp2i(e - 6);
    #pragma unroll
    for (int k = 0; k < CH; ++k)
        __builtin_nontemporal_store(quant4(v[k], s, inv), &o4[k * NT + t]);
}

__global__ __launch_bounds__(NT) void bq_fix(const float* __restrict__ x,
                                             float* __restrict__ out,
                                             const float* __restrict__ partial) {
    const int t = threadIdx.x;
    float g = 0.0f;
    #pragma unroll
    for (int k = 0; k < NB / NT; ++k)
        g = fmaxf(g, partial[t + k * NT]);
    const float mg = block_max_reduce(g, t);
    const int eg = exp_floor(mg);

    if (exp_floor(partial[blockIdx.x]) == eg) return;  // uniform exit (expected: all)

    const v4f* __restrict__ x4 = (const v4f*)x + (size_t)blockIdx.x * (NT * CH);
    v4f* __restrict__ o4 = (v4f*)out + (size_t)blockIdx.x * (NT * CH);
    const float s = exp2i(6 - eg), inv = exp2i(eg - 6);
    #pragma unroll
    for (int k = 0; k < CH; ++k)
        __builtin_nontemporal_store(quant4(x4[k * NT + t], s, inv), &o4[k * NT + t]);
}

// ---------------- fallback: proven R4 two-pass ----------------

__global__ __launch_bounds__(256) void bq_absmax(const float* __restrict__ x,
                                                 float* __restrict__ partial,
                                                 int n) {
    const int n4 = n >> 2;
    const v4f* __restrict__ x4 = (const v4f*)x;
    int tid = blockIdx.x * blockDim.x + threadIdx.x;
    int stride = gridDim.x * blockDim.x;
    float m = 0.0f;
    for (int i = tid; i < n4; i += stride) m = fmaxf(m, absmax4(x4[i]));
    for (int i = (n4 << 2) + tid; i < n; i += stride) m = fmaxf(m, fabsf(x[i]));
    const float mb = block_max_reduce(m, threadIdx.x);
    if (threadIdx.x == 0) partial[blockIdx.x] = mb;
}

__global__ __launch_bounds__(256) void bq_quant(const float* __restrict__ x,
                                                float* __restrict__ out,
                                                const float* __restrict__ partial,
                                                int n) {
    float bm = 0.0f;
    #pragma unroll
    for (int k = 0; k < GRID1 / 256; ++k)
        bm = fmaxf(bm, partial[threadIdx.x + k * 256]);
    const float maxe = block_max_reduce(bm, threadIdx.x);

    const int n4 = n >> 2;
    const v4f* __restrict__ x4 = (const v4f*)x;
    v4f* __restrict__ o4 = (v4f*)out;
    const int tid = blockIdx.x * blockDim.x + threadIdx.x;
    const int T = gridDim.x * blockDim.x;

    if (maxe == 0.0f) {
        for (int i = tid; i < n4; i += T)
            __builtin_nontemporal_store(x4[i], &o4[i]);
        for (int i = (n4 << 2) + tid; i < n; i += T) out[i] = x[i];
        return;
    }
    int e = ilogbf(maxe);
    e = max(-128, min(127, e));
    const float scale    = ldexpf(1.0f, -e + 6);
    const float invscale = ldexpf(1.0f, e - 6);
    for (int i = tid; i < n4; i += T)
        __builtin_nontemporal_store(quant4(x4[i], scale, invscale), &o4[i]);
    for (int i = (n4 << 2) + tid; i < n; i += T) {
        float a = rintf(x[i] * scale);
        a = fminf(fmaxf(a, -128.0f), 127.0f);
        out[i] = a * invscale;
    }
}

extern "C" void kernel_launch(void* const* d_in, const int* in_sizes, int n_in,
                              void* d_out, int out_size, void* d_ws, size_t ws_size,
                              hipStream_t stream) {
    const float* x = (const float*)d_in[0];
    float* out = (float*)d_out;
    int n = in_sizes[0];

    // ws layout: [partial: NB floats][ws2: NB0 floats]
    float* partial = (float*)d_ws;
    float* ws2 = partial + NB;
    const size_t need = (size_t)(NB + NB0) * sizeof(float);

    const long need_n = (long)NB * NT * CH * 4;
    if ((long)n == need_n && ws_size >= need) {
        hipLaunchKernelGGL(bq_sample, dim3(NB0), dim3(NT), 0, stream, x, ws2);
        hipLaunchKernelGGL(bq_spec,   dim3(NB),  dim3(NT), 0, stream, x, out, partial, ws2);
        hipLaunchKernelGGL(bq_fix,    dim3(NB),  dim3(NT), 0, stream, x, out, partial);
    } else {
        hipLaunchKernelGGL(bq_absmax, dim3(GRID1), dim3(256), 0, stream, x, partial, n);
        hipLaunchKernelGGL(bq_quant,  dim3(GRID1), dim3(256), 0, stream, x, out, partial, n);
    }
}

// Round 13
// 73.872 us; speedup vs baseline: 1.0471x; 1.0471x over previous
//
#include <hip/hip_runtime.h>
#include <math.h>

// SWALP global block-quantize, sampled-bound speculate+fix (R13):
//   k0: sparse strided sample (every 256th float4, 50176 lines, ~3 MB) ->
//       per-block max -> ws2[196]. Sampled lower bound Ms.
//   k1: block loads its 1792-float4 slice (7/thread), merges Ms, block max ->
//       partial[b] = max(mb, Ms); quantize with exp_floor(partial[b]) (== e_g
//       for all blocks when Ms lands in the global max's pow2 bucket), nt-store.
//   k2a: ONE block reduces partial[7168] -> mg -> ws2[MG_SLOT].  (~1.5 us)
//   k2b: per-block: eg = exp_floor(mg) via L2 broadcast; exp match -> exit
//        (expected: all); stragglers requantize from x with e_g -> bit-exact.
// Deterministic: fix set is a pure function of the input. Traffic ~ 3 + 205.5R
// + 205.5W ≈ 414 MB. R12's waste removed: k0 was 13 MB/8 us, k2 did 200 MB of
// redundant L2 partial-reads (~7 us); now ~3 + 3 us.

#define NT 256
#define NB0 196                 // sample blocks: 196*256 = 50176 = n4/256
#define SAMPLE_N 50176
#define NB 7168                 // spec blocks; NB*NT*CH*4 == n exactly
#define CH 7                    // float4 per thread
#define MG_SLOT (NB0 + 4)       // ws2 slot for global max
#define GRID1 2048              // fallback grid

typedef float v4f __attribute__((ext_vector_type(4)));

__device__ inline int exp_floor(float m) {          // floor(log2|m|), floored at -120
    int eb = (int)((__float_as_uint(m) >> 23) & 0xff);
    int e = (eb == 0) ? -120 : eb - 127;
    return max(-120, min(127, e));
}
__device__ inline float exp2i(int k) {              // 2^k, k in [-126,127]
    return __uint_as_float((unsigned)(k + 127) << 23);
}
__device__ inline float absmax4(v4f v) {
    return fmaxf(fmaxf(fabsf(v.x), fabsf(v.y)), fmaxf(fabsf(v.z), fabsf(v.w)));
}
__device__ inline v4f quant4(v4f v, float s, float inv) {
    float a = fminf(fmaxf(rintf(v.x * s), -128.0f), 127.0f);
    float b = fminf(fmaxf(rintf(v.y * s), -128.0f), 127.0f);
    float c = fminf(fmaxf(rintf(v.z * s), -128.0f), 127.0f);
    float d = fminf(fmaxf(rintf(v.w * s), -128.0f), 127.0f);
    v4f r;
    r.x = a * inv; r.y = b * inv; r.z = c * inv; r.w = d * inv;
    return r;
}
__device__ inline float block_max_reduce(float m, int t) {
    #pragma unroll
    for (int off = 32; off > 0; off >>= 1)
        m = fmaxf(m, __shfl_xor(m, off, 64));
    __shared__ float sm[4];
    if ((t & 63) == 0) sm[t >> 6] = m;
    __syncthreads();
    return fmaxf(fmaxf(sm[0], sm[1]), fmaxf(sm[2], sm[3]));
}

__global__ __launch_bounds__(NT) void bq_sample(const float* __restrict__ x,
                                                float* __restrict__ ws2) {
    const v4f* __restrict__ x4 = (const v4f*)x;
    const int gtid = blockIdx.x * NT + threadIdx.x;   // exactly SAMPLE_N threads
    float m = absmax4(x4[(size_t)gtid << 8]);         // every 256th float4
    const float mb = block_max_reduce(m, threadIdx.x);
    if (threadIdx.x == 0) ws2[blockIdx.x] = mb;
}

__global__ __launch_bounds__(NT) void bq_spec(const float* __restrict__ x,
                                              float* __restrict__ out,
                                              float* __restrict__ partial,
                                              const float* __restrict__ ws2) {
    const v4f* __restrict__ x4 = (const v4f*)x + (size_t)blockIdx.x * (NT * CH);
    v4f* __restrict__ o4 = (v4f*)out + (size_t)blockIdx.x * (NT * CH);
    const int t = threadIdx.x;

    v4f v[CH];
    #pragma unroll
    for (int k = 0; k < CH; ++k)
        v[k] = x4[k * NT + t];

    float m = (t < NB0) ? ws2[t] : 0.0f;   // merge sampled bound Ms
    #pragma unroll
    for (int k = 0; k < CH; ++k)
        m = fmaxf(m, absmax4(v[k]));
    const float mb = block_max_reduce(m, t);   // = max(block max, Ms)
    if (t == 0) partial[blockIdx.x] = mb;

    const int e = exp_floor(mb);
    const float s = exp2i(6 - e), inv = exp2i(e - 6);
    #pragma unroll
    for (int k = 0; k < CH; ++k)
        __builtin_nontemporal_store(quant4(v[k], s, inv), &o4[k * NT + t]);
}

__global__ __launch_bounds__(NT) void bq_redmax(const float* __restrict__ partial,
                                                float* __restrict__ ws2) {
    const int t = threadIdx.x;
    float g = 0.0f;
    #pragma unroll
    for (int k = 0; k < NB / NT; ++k)
        g = fmaxf(g, partial[t + k * NT]);
    const float mg = block_max_reduce(g, t);
    if (t == 0) ws2[MG_SLOT] = mg;
}

__global__ __launch_bounds__(NT) void bq_fix(const float* __restrict__ x,
                                             float* __restrict__ out,
                                             const float* __restrict__ partial,
                                             const float* __restrict__ ws2) {
    const int eg = exp_floor(ws2[MG_SLOT]);            // L2 broadcast scalar
    if (exp_floor(partial[blockIdx.x]) == eg) return;  // uniform exit (expected: all)

    const int t = threadIdx.x;
    const v4f* __restrict__ x4 = (const v4f*)x + (size_t)blockIdx.x * (NT * CH);
    v4f* __restrict__ o4 = (v4f*)out + (size_t)blockIdx.x * (NT * CH);
    const float s = exp2i(6 - eg), inv = exp2i(eg - 6);
    #pragma unroll
    for (int k = 0; k < CH; ++k)
        __builtin_nontemporal_store(quant4(x4[k * NT + t], s, inv), &o4[k * NT + t]);
}

// ---------------- fallback: proven R4 two-pass ----------------

__global__ __launch_bounds__(256) void bq_absmax(const float* __restrict__ x,
                                                 float* __restrict__ partial,
                                                 int n) {
    const int n4 = n >> 2;
    const v4f* __restrict__ x4 = (const v4f*)x;
    int tid = blockIdx.x * blockDim.x + threadIdx.x;
    int stride = gridDim.x * blockDim.x;
    float m = 0.0f;
    for (int i = tid; i < n4; i += stride) m = fmaxf(m, absmax4(x4[i]));
    for (int i = (n4 << 2) + tid; i < n; i += stride) m = fmaxf(m, fabsf(x[i]));
    const float mb = block_max_reduce(m, threadIdx.x);
    if (threadIdx.x == 0) partial[blockIdx.x] = mb;
}

__global__ __launch_bounds__(256) void bq_quant(const float* __restrict__ x,
                                                float* __restrict__ out,
                                                const float* __restrict__ partial,
                                                int n) {
    float bm = 0.0f;
    #pragma unroll
    for (int k = 0; k < GRID1 / 256; ++k)
        bm = fmaxf(bm, partial[threadIdx.x + k * 256]);
    const float maxe = block_max_reduce(bm, threadIdx.x);

    const int n4 = n >> 2;
    const v4f* __restrict__ x4 = (const v4f*)x;
    v4f* __restrict__ o4 = (v4f*)out;
    const int tid = blockIdx.x * blockDim.x + threadIdx.x;
    const int T = gridDim.x * blockDim.x;

    if (maxe == 0.0f) {
        for (int i = tid; i < n4; i += T)
            __builtin_nontemporal_store(x4[i], &o4[i]);
        for (int i = (n4 << 2) + tid; i < n; i += T) out[i] = x[i];
        return;
    }
    int e = ilogbf(maxe);
    e = max(-128, min(127, e));
    const float scale    = ldexpf(1.0f, -e + 6);
    const float invscale = ldexpf(1.0f, e - 6);
    for (int i = tid; i < n4; i += T)
        __builtin_nontemporal_store(quant4(x4[i], scale, invscale), &o4[i]);
    for (int i = (n4 << 2) + tid; i < n; i += T) {
        float a = rintf(x[i] * scale);
        a = fminf(fmaxf(a, -128.0f), 127.0f);
        out[i] = a * invscale;
    }
}

extern "C" void kernel_launch(void* const* d_in, const int* in_sizes, int n_in,
                              void* d_out, int out_size, void* d_ws, size_t ws_size,
                              hipStream_t stream) {
    const float* x = (const float*)d_in[0];
    float* out = (float*)d_out;
    int n = in_sizes[0];

    // ws layout: [partial: NB floats][ws2: NB0+8 floats]
    float* partial = (float*)d_ws;
    float* ws2 = partial + NB;
    const size_t need = (size_t)(NB + MG_SLOT + 8) * sizeof(float);

    const long need_n = (long)NB * NT * CH * 4;
    if ((long)n == need_n && ws_size >= need) {
        hipLaunchKernelGGL(bq_sample, dim3(NB0), dim3(NT), 0, stream, x, ws2);
        hipLaunchKernelGGL(bq_spec,   dim3(NB),  dim3(NT), 0, stream, x, out, partial, ws2);
        hipLaunchKernelGGL(bq_redmax, dim3(1),   dim3(NT), 0, stream, partial, ws2);
        hipLaunchKernelGGL(bq_fix,    dim3(NB),  dim3(NT), 0, stream, x, out, partial, ws2);
    } else {
        hipLaunchKernelGGL(bq_absmax, dim3(GRID1), dim3(256), 0, stream, x, partial, n);
        hipLaunchKernelGGL(bq_quant,  dim3(GRID1), dim3(256), 0, stream, x, out, partial, n);
    }
}